// Round 4
// baseline (399.585 us; speedup 1.0000x reference)
//
#include <hip/hip_runtime.h>

// ---------------------------------------------------------------------------
// QalbAttention: x->(Q,K,V) proj + RoPE, per-batch temperature scale,
// causal flash attention, output projection.
// B=2, N=2048, D=1024, H=16, HD=64.  All matmuls in bf16 MFMA (16x16x32),
// fp32 accumulate. Tolerance is bf16-grade (threshold ~2.5e-2).
//
// R3: attn rewritten barrier-free (K/V read direct from global, L2-resident;
// V pre-transposed by vtrans_kernel; XCD-swizzled grid). Baseline attn was
// latency-bound: MfmaUtil 4.3%, Occ 13%, 2 barriers/iter.
// ---------------------------------------------------------------------------

typedef short short8 __attribute__((ext_vector_type(8)));      // 8 bf16 (4 VGPR)
typedef float floatx4 __attribute__((ext_vector_type(4)));
typedef unsigned int uint4v __attribute__((ext_vector_type(4)));
typedef unsigned short us4 __attribute__((ext_vector_type(4)));
typedef unsigned short u16;

#define DEV __device__ __forceinline__

static const int Bb = 2, Nn = 2048, Dd = 1024, Hh = 16, HD = 64;

// ws layout (bytes)
static const size_t OFF_XB = 0;                       // x bf16 (4096x1024) 8MB; dead after gemm_qkv -> reused as V^T
static const size_t OFF_WQ = 8388608;                 // Wq bf16  (1024x1024)  2MB
static const size_t OFF_WK = OFF_WQ + 2097152;
static const size_t OFF_WV = OFF_WK + 2097152;
static const size_t OFF_WO = OFF_WV + 2097152;
static const size_t OFF_Q  = OFF_WO + 2097152;        // (B,H,N,HD) bf16 8MB
static const size_t OFF_K  = OFF_Q + 8388608;
static const size_t OFF_V  = OFF_K + 8388608;
static const size_t OFF_AO = OFF_V + 8388608;         // (M,D) bf16 8MB
static const size_t OFF_SC = OFF_AO + 8388608;        // [0:2) inv_scale, [2:4) partials

DEV u16 f2bf(float f) {                               // RNE float->bf16
  unsigned int u = __builtin_bit_cast(unsigned int, f);
  u += 0x7fffu + ((u >> 16) & 1u);
  return (u16)(u >> 16);
}

// --------------------------- fp32 -> bf16 convert ---------------------------
__global__ void cvt_kernel(const float* __restrict__ src, u16* __restrict__ dst, int n4) {
  int i = blockIdx.x * 256 + threadIdx.x;
  if (i >= n4) return;
  float4 f = ((const float4*)src)[i];
  us4 o;
  o[0] = f2bf(f.x); o[1] = f2bf(f.y); o[2] = f2bf(f.z); o[3] = f2bf(f.w);
  ((us4*)dst)[i] = o;
}

// --------------------------- temperature scale ------------------------------
__global__ void scale_partial_kernel(const float* __restrict__ x,
                                     const float* __restrict__ cw,
                                     float* __restrict__ part) {
  int blk = blockIdx.x;            // 128 blocks: 64 per batch
  int b = blk >> 6, sl = blk & 63;
  const float4* xp = (const float4*)(x + (size_t)b * 2097152) + (size_t)sl * 8192;
  float acc = 0.f;
  for (int i = threadIdx.x; i < 8192; i += 256) {
    float4 f = xp[i];
    int d4 = (sl * 8192 + i) & 255;     // (D/4)=256
    float4 c = ((const float4*)cw)[d4];
    acc += f.x * c.x + f.y * c.y + f.z * c.z + f.w * c.w;
  }
  __shared__ float red[256];
  red[threadIdx.x] = acc;
  __syncthreads();
  for (int s = 128; s > 0; s >>= 1) {
    if (threadIdx.x < s) red[threadIdx.x] += red[threadIdx.x + s];
    __syncthreads();
  }
  if (threadIdx.x == 0) atomicAdd(&part[b], red[0]);
}

__global__ void scale_finalize_kernel(const float* __restrict__ part,
                                      const float* __restrict__ cb,
                                      const float* __restrict__ alpha,
                                      const float* __restrict__ tb,
                                      const int* __restrict__ tstep,
                                      float* __restrict__ out) {
  int b = threadIdx.x;
  if (b >= Bb) return;
  float sm = part[b] * (1.0f / 2048.0f) + cb[0];
  float cx = 1.0f / (1.0f + expf(-sm));
  float Te = (fabsf(tb[0]) + 1.0f) * (0.5f + cx);
  float psi = 1.0f + alpha[0] * sinf(6.283185307179586f * (float)tstep[0] / Te);
  out[b] = 1.0f / (8.0f * psi);        // scores get multiplied by this
}

// --------------------------- QKV GEMM + RoPE --------------------------------
// C[m,e] = sum_k A[m,k]*W[e,k]; 128x128 tile, BK=32, 4 waves 2x2, 4x4 frags.
__global__ __launch_bounds__(256) void gemm_qkv_kernel(
    const u16* __restrict__ xb, const u16* __restrict__ wq, const u16* __restrict__ wk,
    const u16* __restrict__ wv, u16* __restrict__ q, u16* __restrict__ k,
    u16* __restrict__ v) {
  const int tm = blockIdx.x, tn = blockIdx.y, which = blockIdx.z;
  const u16* W = (which == 0) ? wq : (which == 1) ? wk : wv;
  u16* dst = (which == 0) ? q : (which == 1) ? k : v;

  __shared__ __align__(16) u16 As[128 * 32];
  __shared__ __align__(16) u16 Bs[128 * 32];

  const int t = threadIdx.x, lane = t & 63, w = t >> 6;
  const int wm = w >> 1, wn = w & 1, lg = lane >> 4, lr = lane & 15;

  floatx4 acc[4][4];
#pragma unroll
  for (int i = 0; i < 4; i++)
#pragma unroll
    for (int j = 0; j < 4; j++) acc[i][j] = (floatx4){0.f, 0.f, 0.f, 0.f};

  const int rowA = tm * 128, rowB = tn * 128;
  for (int kt = 0; kt < 32; ++kt) {
#pragma unroll
    for (int s = 0; s < 2; s++) {
      int c = t + s * 256;
      int r = c >> 2, kc = c & 3;     // 32 bf16/row = 4 x 16B chunks
      *(uint4v*)(As + r * 32 + kc * 8) =
          *(const uint4v*)(xb + (size_t)(rowA + r) * 1024 + kt * 32 + kc * 8);
      *(uint4v*)(Bs + r * 32 + kc * 8) =
          *(const uint4v*)(W + (size_t)(rowB + r) * 1024 + kt * 32 + kc * 8);
    }
    __syncthreads();
    short8 af[4], bw[4];
#pragma unroll
    for (int i = 0; i < 4; i++)
      af[i] = *(const short8*)(As + (wm * 64 + i * 16 + lr) * 32 + lg * 8);
#pragma unroll
    for (int j = 0; j < 4; j++)
      bw[j] = *(const short8*)(Bs + (wn * 64 + j * 16 + lr) * 32 + lg * 8);
#pragma unroll
    for (int i = 0; i < 4; i++)
#pragma unroll
      for (int j = 0; j < 4; j++)
        acc[i][j] = __builtin_amdgcn_mfma_f32_16x16x32_bf16(af[i], bw[j], acc[i][j], 0, 0, 0);
    __syncthreads();
  }

  const int rowbase = tm * 128 + wm * 64, colbase = tn * 128 + wn * 64;
  if (which <= 1) {
    // RoPE epilogue: partner hd±32 is frag j±2 in the SAME lane, same angle.
#pragma unroll
    for (int i = 0; i < 4; i++)
#pragma unroll
      for (int ii = 0; ii < 4; ii++) {
        int gm = rowbase + i * 16 + lg * 4 + ii;
        int pos = gm & 2047, bb = gm >> 11;
#pragma unroll
        for (int jp = 0; jp < 2; jp++) {
          int hd2 = jp * 16 + lr;                           // 0..31
          float ang = (float)pos * exp2f(-(float)hd2 * 0.41524101186092030f);
          float sv, cv;
          sincosf(ang, &sv, &cv);
          float a0 = acc[i][jp][ii], a1 = acc[i][jp + 2][ii];
          int e0 = colbase + jp * 16 + lr;
          int hh = e0 >> 6;
          size_t base = (((size_t)bb * 16 + hh) * 2048 + pos) * 64;
          dst[base + hd2]      = f2bf(a0 * cv - a1 * sv);   // hd < 32
          dst[base + hd2 + 32] = f2bf(a1 * cv + a0 * sv);   // hd >= 32
        }
      }
  } else {
#pragma unroll
    for (int i = 0; i < 4; i++)
#pragma unroll
      for (int ii = 0; ii < 4; ii++) {
        int gm = rowbase + i * 16 + lg * 4 + ii;
        int pos = gm & 2047, bb = gm >> 11;
#pragma unroll
        for (int j = 0; j < 4; j++) {
          int ge = colbase + j * 16 + lr;
          int hh = ge >> 6, hd = ge & 63;
          dst[(((size_t)bb * 16 + hh) * 2048 + pos) * 64 + hd] = f2bf(acc[i][j][ii]);
        }
      }
  }
}

// --------------------------- V transpose ------------------------------------
// v [bh][n][64] -> vt [bh][64][n] (bh=32, n=2048). 64x64 LDS tiles, swizzled.
__global__ __launch_bounds__(256) void vtrans_kernel(const u16* __restrict__ v,
                                                     u16* __restrict__ vt) {
  const int bh = blockIdx.x, nt = blockIdx.y;     // 32 x 32
  __shared__ __align__(16) u16 T[64 * 64];
  const int t = threadIdx.x;
  const size_t vi = (size_t)bh * 131072 + (size_t)nt * 4096;
#pragma unroll
  for (int s = 0; s < 2; s++) {
    int g = s * 256 + t, n = g >> 3, dc = g & 7;
    *(uint4v*)(T + n * 64 + ((dc ^ (n & 7)) * 8)) =
        *(const uint4v*)(v + vi + (size_t)n * 64 + dc * 8);
  }
  __syncthreads();
  const size_t vo = (size_t)bh * 131072 + (size_t)nt * 64;
#pragma unroll
  for (int s = 0; s < 2; s++) {
    int g = s * 256 + t, nc = g & 7, d = g >> 3;
    short8 o;
#pragma unroll
    for (int jj = 0; jj < 8; jj++) {
      int n = nc * 8 + jj;
      o[jj] = (short)T[n * 64 + (((d >> 3) ^ (n & 7)) * 8) + (d & 7)];
    }
    *(short8*)(vt + vo + (size_t)d * 2048 + nc * 8) = o;
  }
}

// --------------------------- flash attention --------------------------------
// Barrier-free: 1024 blocks (XCD-swizzled), 4 independent waves each owning 16
// Q rows. K and V^T fragments read directly from global (L2-resident, 256KB/head).
// Only LDS use: wave-private P round-trip (same-wave DS order, no barrier).
__global__ __launch_bounds__(256) void attn_kernel(
    const u16* __restrict__ q, const u16* __restrict__ k, const u16* __restrict__ vt,
    u16* __restrict__ ao, const float* __restrict__ scale_ws) {
  const int lin = blockIdx.x;
  const int swz = (lin & 7) * 128 + (lin >> 3);   // XCD x gets hb in [4x,4x+4)
  const int qt = swz & 31;
  const int hb = swz >> 5;                        // b*16+h
  const int b = hb >> 4, h = hb & 15;
  const float isc = scale_ws[b];

  __shared__ __align__(16) u16 Ps[64 * 64];       // 8KB, partitioned by wave

  const int t = threadIdx.x, lane = t & 63, w = t >> 6, lg = lane >> 4, lr = lane & 15;
  const size_t hoff = (size_t)hb * 131072;        // q,k: [bh][n][64]
  const size_t voff = (size_t)hb * 131072;        // vt:  [bh][64][n]
  const float LOG2E = 1.4426950408889634f;

  // Q fragments, hoisted (A-operand row = lr)
  const int qrow = qt * 64 + 16 * w + lr;
  const short8 aq0 = *(const short8*)(q + hoff + (size_t)qrow * 64 + lg * 8);
  const short8 aq1 = *(const short8*)(q + hoff + (size_t)qrow * 64 + 32 + lg * 8);

  floatx4 o[4];
#pragma unroll
  for (int n = 0; n < 4; n++) o[n] = (floatx4){0.f, 0.f, 0.f, 0.f};
  float mrow[4] = {-__builtin_inff(), -__builtin_inff(), -__builtin_inff(), -__builtin_inff()};
  float lrow[4] = {0.f, 0.f, 0.f, 0.f};

  for (int kt = 0; kt <= qt; ++kt) {
    // ---- S = Q K^T : K row-fragments straight from global ----
    float sf[4][4];
#pragma unroll
    for (int n = 0; n < 4; n++) {
      const u16* kp = k + hoff + (size_t)(kt * 64 + 16 * n + lr) * 64;
      short8 b0 = *(const short8*)(kp + lg * 8);
      short8 b1 = *(const short8*)(kp + 32 + lg * 8);
      floatx4 sacc = (floatx4){0.f, 0.f, 0.f, 0.f};
      sacc = __builtin_amdgcn_mfma_f32_16x16x32_bf16(aq0, b0, sacc, 0, 0, 0);
      sacc = __builtin_amdgcn_mfma_f32_16x16x32_bf16(aq1, b1, sacc, 0, 0, 0);
#pragma unroll
      for (int ii = 0; ii < 4; ii++) sf[n][ii] = sacc[ii] * isc;
    }
    if (kt == qt) {   // diagonal tile: causal mask (uniform branch)
#pragma unroll
      for (int n = 0; n < 4; n++)
#pragma unroll
        for (int ii = 0; ii < 4; ii++) {
          int colg = 16 * n + lr, rowg = 16 * w + lg * 4 + ii;
          if (colg > rowg) sf[n][ii] = -__builtin_inff();
        }
    }

    // ---- online softmax (rows lg*4+ii; reduce over 16 lr lanes) ----
    float resc[4];
#pragma unroll
    for (int ii = 0; ii < 4; ii++) {
      float mx = fmaxf(fmaxf(sf[0][ii], sf[1][ii]), fmaxf(sf[2][ii], sf[3][ii]));
      mx = fmaxf(mx, __shfl_xor(mx, 1, 64));
      mx = fmaxf(mx, __shfl_xor(mx, 2, 64));
      mx = fmaxf(mx, __shfl_xor(mx, 4, 64));
      mx = fmaxf(mx, __shfl_xor(mx, 8, 64));
      float mnew = fmaxf(mrow[ii], mx);
      resc[ii] = exp2f((mrow[ii] - mnew) * LOG2E);
      mrow[ii] = mnew;
    }
    float psum[4] = {0.f, 0.f, 0.f, 0.f};
#pragma unroll
    for (int n = 0; n < 4; n++)
#pragma unroll
      for (int ii = 0; ii < 4; ii++) {
        float p = exp2f((sf[n][ii] - mrow[ii]) * LOG2E);
        sf[n][ii] = p;                 // reuse sf as P
        psum[ii] += p;
      }
#pragma unroll
    for (int ii = 0; ii < 4; ii++) {
      float su = psum[ii];
      su += __shfl_xor(su, 1, 64);
      su += __shfl_xor(su, 2, 64);
      su += __shfl_xor(su, 4, 64);
      su += __shfl_xor(su, 8, 64);
      lrow[ii] = lrow[ii] * resc[ii] + su;
    }
#pragma unroll
    for (int n = 0; n < 4; n++)
#pragma unroll
      for (int ii = 0; ii < 4; ii++) o[n][ii] *= resc[ii];

    // ---- P -> LDS (wave-private rows; same-wave RAW via lgkmcnt) ----
#pragma unroll
    for (int n = 0; n < 4; n++)
#pragma unroll
      for (int ii = 0; ii < 4; ii++) {
        int pr = 16 * w + lg * 4 + ii;
        int pc = n * 16 + lr;
        Ps[pr * 64 + (((pc >> 3) ^ (pr & 7)) * 8) + (pc & 7)] = f2bf(sf[n][ii]);
      }

    // ---- O += P V : V^T row-fragments straight from global ----
#pragma unroll
    for (int kk = 0; kk < 2; kk++) {
      int prow = 16 * w + lr;
      short8 ap = *(const short8*)(Ps + prow * 64 + (((kk * 4 + lg) ^ (prow & 7)) * 8));
#pragma unroll
      for (int n = 0; n < 4; n++) {
        short8 bv = *(const short8*)(vt + voff + (size_t)(16 * n + lr) * 2048 +
                                     kt * 64 + kk * 32 + lg * 8);
        o[n] = __builtin_amdgcn_mfma_f32_16x16x32_bf16(ap, bv, o[n], 0, 0, 0);
      }
    }
  }

#pragma unroll
  for (int ii = 0; ii < 4; ii++) {
    float invl = 1.0f / lrow[ii];
    int rowg = qt * 64 + 16 * w + lg * 4 + ii;
    size_t rb = ((size_t)(b * 2048 + rowg)) * 1024 + h * 64;
#pragma unroll
    for (int n = 0; n < 4; n++) ao[rb + n * 16 + lr] = f2bf(o[n][ii] * invl);
  }
}

// --------------------------- output projection ------------------------------
__global__ __launch_bounds__(256) void gemm_out_kernel(const u16* __restrict__ ab,
                                                       const u16* __restrict__ wo,
                                                       float* __restrict__ out) {
  const int tm = blockIdx.x, tn = blockIdx.y;
  __shared__ __align__(16) u16 As[128 * 32];
  __shared__ __align__(16) u16 Bs[128 * 32];

  const int t = threadIdx.x, lane = t & 63, w = t >> 6;
  const int wm = w >> 1, wn = w & 1, lg = lane >> 4, lr = lane & 15;

  floatx4 acc[4][4];
#pragma unroll
  for (int i = 0; i < 4; i++)
#pragma unroll
    for (int j = 0; j < 4; j++) acc[i][j] = (floatx4){0.f, 0.f, 0.f, 0.f};

  const int rowA = tm * 128, rowB = tn * 128;
  for (int kt = 0; kt < 32; ++kt) {
#pragma unroll
    for (int s = 0; s < 2; s++) {
      int c = t + s * 256;
      int r = c >> 2, kc = c & 3;
      *(uint4v*)(As + r * 32 + kc * 8) =
          *(const uint4v*)(ab + (size_t)(rowA + r) * 1024 + kt * 32 + kc * 8);
      *(uint4v*)(Bs + r * 32 + kc * 8) =
          *(const uint4v*)(wo + (size_t)(rowB + r) * 1024 + kt * 32 + kc * 8);
    }
    __syncthreads();
    short8 af[4], bw[4];
#pragma unroll
    for (int i = 0; i < 4; i++)
      af[i] = *(const short8*)(As + (wm * 64 + i * 16 + lr) * 32 + lg * 8);
#pragma unroll
    for (int j = 0; j < 4; j++)
      bw[j] = *(const short8*)(Bs + (wn * 64 + j * 16 + lr) * 32 + lg * 8);
#pragma unroll
    for (int i = 0; i < 4; i++)
#pragma unroll
      for (int j = 0; j < 4; j++)
        acc[i][j] = __builtin_amdgcn_mfma_f32_16x16x32_bf16(af[i], bw[j], acc[i][j], 0, 0, 0);
    __syncthreads();
  }

  const int rowbase = tm * 128 + wm * 64, colbase = tn * 128 + wn * 64;
#pragma unroll
  for (int i = 0; i < 4; i++)
#pragma unroll
    for (int ii = 0; ii < 4; ii++) {
      int gm = rowbase + i * 16 + lg * 4 + ii;
#pragma unroll
      for (int j = 0; j < 4; j++) {
        int ge = colbase + j * 16 + lr;
        out[(size_t)gm * 1024 + ge] = acc[i][j][ii];
      }
    }
}

// ---------------------------------------------------------------------------
extern "C" void kernel_launch(void* const* d_in, const int* in_sizes, int n_in,
                              void* d_out, int out_size, void* d_ws, size_t ws_size,
                              hipStream_t stream) {
  const float* x     = (const float*)d_in[0];
  const float* Wq    = (const float*)d_in[1];
  const float* Wk    = (const float*)d_in[2];
  const float* Wv    = (const float*)d_in[3];
  const float* Wo    = (const float*)d_in[4];
  const float* alpha = (const float*)d_in[5];
  const float* Tb    = (const float*)d_in[6];
  const float* cw    = (const float*)d_in[7];
  const float* cb    = (const float*)d_in[8];
  const int*   tstep = (const int*)d_in[11];

  char* ws = (char*)d_ws;
  u16* xb  = (u16*)(ws + OFF_XB);
  u16* wqb = (u16*)(ws + OFF_WQ);
  u16* wkb = (u16*)(ws + OFF_WK);
  u16* wvb = (u16*)(ws + OFF_WV);
  u16* wob = (u16*)(ws + OFF_WO);
  u16* qb  = (u16*)(ws + OFF_Q);
  u16* kb  = (u16*)(ws + OFF_K);
  u16* vb  = (u16*)(ws + OFF_V);
  u16* aob = (u16*)(ws + OFF_AO);
  u16* vtb = (u16*)(ws + OFF_XB);           // aliases xb (dead after gemm_qkv)
  float* sc = (float*)(ws + OFF_SC);        // [0:2) inv_scale, [2:4) partials

  // bf16 converts
  cvt_kernel<<<4096, 256, 0, stream>>>(x, xb, 1048576);
  cvt_kernel<<<1024, 256, 0, stream>>>(Wq, wqb, 262144);
  cvt_kernel<<<1024, 256, 0, stream>>>(Wk, wkb, 262144);
  cvt_kernel<<<1024, 256, 0, stream>>>(Wv, wvb, 262144);
  cvt_kernel<<<1024, 256, 0, stream>>>(Wo, wob, 262144);

  // temperature scale
  hipMemsetAsync(sc + 2, 0, 2 * sizeof(float), stream);
  scale_partial_kernel<<<128, 256, 0, stream>>>(x, cw, sc + 2);
  scale_finalize_kernel<<<1, 64, 0, stream>>>(sc + 2, cb, alpha, Tb, tstep, sc);

  // QKV projection + RoPE
  gemm_qkv_kernel<<<dim3(32, 8, 3), 256, 0, stream>>>(xb, wqb, wkb, wvb, qb, kb, vb);

  // V -> V^T (into dead xb region)
  vtrans_kernel<<<dim3(32, 32), 256, 0, stream>>>(vb, vtb);

  // causal flash attention (barrier-free, XCD-swizzled 1D grid)
  attn_kernel<<<dim3(1024), 256, 0, stream>>>(qb, kb, vtb, aob, sc);

  // output projection
  gemm_out_kernel<<<dim3(32, 8), 256, 0, stream>>>(aob, wob, (float*)d_out);
}

// Round 5
// 282.641 us; speedup vs baseline: 1.4138x; 1.4138x over previous
//
#include <hip/hip_runtime.h>

// ---------------------------------------------------------------------------
// QalbAttention: x->(Q,K,V) proj + RoPE, per-batch temperature scale,
// causal flash attention, output projection.
// B=2, N=2048, D=1024, H=16, HD=64.
//
// R5: attn rewritten on 32x32x16 MFMA with swapped operands (S^T = K·Q):
// softmax lane-local (1 shfl per reduce), P packed in-register via
// v_cvt_pk_bf16_f32 + shfl_xor(32) (no LDS roundtrip), O^T accumulated,
// per-wave 32-row q-tiles paired {p,31-p,32+p,63-p} for constant block work.
// Zero LDS / zero barriers in attn. R3/R4 were latency-chain-bound
// (MfmaUtil 3-4%, occ 14%).
// ---------------------------------------------------------------------------

typedef short short8 __attribute__((ext_vector_type(8)));      // 8 bf16 (4 VGPR)
typedef float floatx4 __attribute__((ext_vector_type(4)));
typedef float f32x16 __attribute__((ext_vector_type(16)));
typedef unsigned int uint4v __attribute__((ext_vector_type(4)));
typedef unsigned int u32x4v __attribute__((ext_vector_type(4)));
typedef unsigned short us4 __attribute__((ext_vector_type(4)));
typedef unsigned short u16;

#define DEV __device__ __forceinline__

static const int Bb = 2;

// ws layout (bytes)
static const size_t OFF_XB = 0;                       // x bf16 (4096x1024) 8MB; dead after gemm_qkv -> reused as V^T
static const size_t OFF_WQ = 8388608;
static const size_t OFF_WK = OFF_WQ + 2097152;
static const size_t OFF_WV = OFF_WK + 2097152;
static const size_t OFF_WO = OFF_WV + 2097152;
static const size_t OFF_Q  = OFF_WO + 2097152;        // (B,H,N,HD) bf16 8MB
static const size_t OFF_K  = OFF_Q + 8388608;
static const size_t OFF_V  = OFF_K + 8388608;
static const size_t OFF_AO = OFF_V + 8388608;         // (M,D) bf16 8MB
static const size_t OFF_SC = OFF_AO + 8388608;        // [0:2) inv_scale, [2:4) partials

DEV u16 f2bf(float f) {                               // RNE float->bf16
  unsigned int u = __builtin_bit_cast(unsigned int, f);
  u += 0x7fffu + ((u >> 16) & 1u);
  return (u16)(u >> 16);
}

DEV unsigned pkbf(float lo, float hi) {               // pack 2xf32 -> 2xbf16 (RNE)
  unsigned r;
  asm("v_cvt_pk_bf16_f32 %0, %1, %2" : "=v"(r) : "v"(lo), "v"(hi));
  return r;
}

// --------------------------- fp32 -> bf16 convert ---------------------------
__global__ void cvt_kernel(const float* __restrict__ src, u16* __restrict__ dst, int n4) {
  int i = blockIdx.x * 256 + threadIdx.x;
  if (i >= n4) return;
  float4 f = ((const float4*)src)[i];
  us4 o;
  o[0] = f2bf(f.x); o[1] = f2bf(f.y); o[2] = f2bf(f.z); o[3] = f2bf(f.w);
  ((us4*)dst)[i] = o;
}

// --------------------------- temperature scale ------------------------------
__global__ void scale_partial_kernel(const float* __restrict__ x,
                                     const float* __restrict__ cw,
                                     float* __restrict__ part) {
  int blk = blockIdx.x;            // 128 blocks: 64 per batch
  int b = blk >> 6, sl = blk & 63;
  const float4* xp = (const float4*)(x + (size_t)b * 2097152) + (size_t)sl * 8192;
  float acc = 0.f;
  for (int i = threadIdx.x; i < 8192; i += 256) {
    float4 f = xp[i];
    int d4 = (sl * 8192 + i) & 255;
    float4 c = ((const float4*)cw)[d4];
    acc += f.x * c.x + f.y * c.y + f.z * c.z + f.w * c.w;
  }
  __shared__ float red[256];
  red[threadIdx.x] = acc;
  __syncthreads();
  for (int s = 128; s > 0; s >>= 1) {
    if (threadIdx.x < s) red[threadIdx.x] += red[threadIdx.x + s];
    __syncthreads();
  }
  if (threadIdx.x == 0) atomicAdd(&part[b], red[0]);
}

__global__ void scale_finalize_kernel(const float* __restrict__ part,
                                      const float* __restrict__ cb,
                                      const float* __restrict__ alpha,
                                      const float* __restrict__ tb,
                                      const int* __restrict__ tstep,
                                      float* __restrict__ out) {
  int b = threadIdx.x;
  if (b >= Bb) return;
  float sm = part[b] * (1.0f / 2048.0f) + cb[0];
  float cx = 1.0f / (1.0f + expf(-sm));
  float Te = (fabsf(tb[0]) + 1.0f) * (0.5f + cx);
  float psi = 1.0f + alpha[0] * sinf(6.283185307179586f * (float)tstep[0] / Te);
  out[b] = 1.0f / (8.0f * psi);
}

// --------------------------- QKV GEMM + RoPE --------------------------------
__global__ __launch_bounds__(256) void gemm_qkv_kernel(
    const u16* __restrict__ xb, const u16* __restrict__ wq, const u16* __restrict__ wk,
    const u16* __restrict__ wv, u16* __restrict__ q, u16* __restrict__ k,
    u16* __restrict__ v) {
  const int tm = blockIdx.x, tn = blockIdx.y, which = blockIdx.z;
  const u16* W = (which == 0) ? wq : (which == 1) ? wk : wv;
  u16* dst = (which == 0) ? q : (which == 1) ? k : v;

  __shared__ __align__(16) u16 As[128 * 32];
  __shared__ __align__(16) u16 Bs[128 * 32];

  const int t = threadIdx.x, lane = t & 63, w = t >> 6;
  const int wm = w >> 1, wn = w & 1, lg = lane >> 4, lr = lane & 15;

  floatx4 acc[4][4];
#pragma unroll
  for (int i = 0; i < 4; i++)
#pragma unroll
    for (int j = 0; j < 4; j++) acc[i][j] = (floatx4){0.f, 0.f, 0.f, 0.f};

  const int rowA = tm * 128, rowB = tn * 128;
  for (int kt = 0; kt < 32; ++kt) {
#pragma unroll
    for (int s = 0; s < 2; s++) {
      int c = t + s * 256;
      int r = c >> 2, kc = c & 3;
      *(uint4v*)(As + r * 32 + kc * 8) =
          *(const uint4v*)(xb + (size_t)(rowA + r) * 1024 + kt * 32 + kc * 8);
      *(uint4v*)(Bs + r * 32 + kc * 8) =
          *(const uint4v*)(W + (size_t)(rowB + r) * 1024 + kt * 32 + kc * 8);
    }
    __syncthreads();
    short8 af[4], bw[4];
#pragma unroll
    for (int i = 0; i < 4; i++)
      af[i] = *(const short8*)(As + (wm * 64 + i * 16 + lr) * 32 + lg * 8);
#pragma unroll
    for (int j = 0; j < 4; j++)
      bw[j] = *(const short8*)(Bs + (wn * 64 + j * 16 + lr) * 32 + lg * 8);
#pragma unroll
    for (int i = 0; i < 4; i++)
#pragma unroll
      for (int j = 0; j < 4; j++)
        acc[i][j] = __builtin_amdgcn_mfma_f32_16x16x32_bf16(af[i], bw[j], acc[i][j], 0, 0, 0);
    __syncthreads();
  }

  const int rowbase = tm * 128 + wm * 64, colbase = tn * 128 + wn * 64;
  if (which <= 1) {
#pragma unroll
    for (int i = 0; i < 4; i++)
#pragma unroll
      for (int ii = 0; ii < 4; ii++) {
        int gm = rowbase + i * 16 + lg * 4 + ii;
        int pos = gm & 2047, bb = gm >> 11;
#pragma unroll
        for (int jp = 0; jp < 2; jp++) {
          int hd2 = jp * 16 + lr;
          float ang = (float)pos * exp2f(-(float)hd2 * 0.41524101186092030f);
          float sv, cv;
          sincosf(ang, &sv, &cv);
          float a0 = acc[i][jp][ii], a1 = acc[i][jp + 2][ii];
          int e0 = colbase + jp * 16 + lr;
          int hh = e0 >> 6;
          size_t base = (((size_t)bb * 16 + hh) * 2048 + pos) * 64;
          dst[base + hd2]      = f2bf(a0 * cv - a1 * sv);
          dst[base + hd2 + 32] = f2bf(a1 * cv + a0 * sv);
        }
      }
  } else {
#pragma unroll
    for (int i = 0; i < 4; i++)
#pragma unroll
      for (int ii = 0; ii < 4; ii++) {
        int gm = rowbase + i * 16 + lg * 4 + ii;
        int pos = gm & 2047, bb = gm >> 11;
#pragma unroll
        for (int j = 0; j < 4; j++) {
          int ge = colbase + j * 16 + lr;
          int hh = ge >> 6, hd = ge & 63;
          dst[(((size_t)bb * 16 + hh) * 2048 + pos) * 64 + hd] = f2bf(acc[i][j][ii]);
        }
      }
  }
}

// --------------------------- V transpose ------------------------------------
__global__ __launch_bounds__(256) void vtrans_kernel(const u16* __restrict__ v,
                                                     u16* __restrict__ vt) {
  const int bh = blockIdx.x, nt = blockIdx.y;     // 32 x 32
  __shared__ __align__(16) u16 T[64 * 64];
  const int t = threadIdx.x;
  const size_t vi = (size_t)bh * 131072 + (size_t)nt * 4096;
#pragma unroll
  for (int s = 0; s < 2; s++) {
    int g = s * 256 + t, n = g >> 3, dc = g & 7;
    *(uint4v*)(T + n * 64 + ((dc ^ (n & 7)) * 8)) =
        *(const uint4v*)(v + vi + (size_t)n * 64 + dc * 8);
  }
  __syncthreads();
  const size_t vo = (size_t)bh * 131072 + (size_t)nt * 64;
#pragma unroll
  for (int s = 0; s < 2; s++) {
    int g = s * 256 + t, nc = g & 7, d = g >> 3;
    short8 o;
#pragma unroll
    for (int jj = 0; jj < 8; jj++) {
      int n = nc * 8 + jj;
      o[jj] = (short)T[n * 64 + (((d >> 3) ^ (n & 7)) * 8) + (d & 7)];
    }
    *(short8*)(vt + vo + (size_t)d * 2048 + nc * 8) = o;
  }
}

// --------------------------- flash attention --------------------------------
// 512 blocks x 4 waves; wave owns a 32-row q-tile (tiles {p,31-p,32+p,63-p}
// per block -> constant block work). S^T = mfma32x32(K,Q): lane&31 = q-row,
// softmax lane-local; P packed to PV B-frags via cvt_pk + shfl_xor(32);
// O^T = mfma32x32(V^T, P). No LDS, no barriers.
__global__ __launch_bounds__(256) void attn_kernel(
    const u16* __restrict__ q, const u16* __restrict__ k, const u16* __restrict__ vt,
    u16* __restrict__ ao, const float* __restrict__ scale_ws) {
  const int bid = blockIdx.x;
  const int swz = (bid & 7) * 64 + (bid >> 3);    // XCD x -> bh in [4x,4x+4)
  const int bh = swz >> 4, p = swz & 15;
  const int b = bh >> 4, h = bh & 15;
  const int w = threadIdx.x >> 6, lane = threadIdx.x & 63;
  const int l31 = lane & 31, hi = lane >> 5;
  const int tsel = (w == 0) ? p : (w == 1) ? 31 - p : (w == 2) ? 32 + p : 63 - p;
  const int q0 = tsel * 32;
  const int KT = tsel >> 1;                        // last 64-col k-tile index
  const float isc2 = scale_ws[b] * 1.4426950408889634f;   // fold log2e
  const size_t koff = (size_t)bh * 131072;
  const float NINF = -__builtin_inff();

  // Q B-frags (col = q = l31, k = k4*16 + hi*8 + e), hoisted
  short8 bq[4];
#pragma unroll
  for (int k4 = 0; k4 < 4; k4++)
    bq[k4] = *(const short8*)(q + koff + (size_t)(q0 + l31) * 64 + k4 * 16 + hi * 8);

  f32x16 o0, o1;
#pragma unroll
  for (int r = 0; r < 16; r++) { o0[r] = 0.f; o1[r] = 0.f; }
  float m2 = NINF, ell = 0.f;

  for (int kt = 0; kt <= KT; ++kt) {
    const int cbase = kt << 6;
    const bool haveMt1 = (cbase + 32 <= q0 + 31);  // false only on even-tile diag

    // ---- issue K fragment loads (A-op: row = c, k = k4*16+hi*8+e) ----
    short8 ka0[4], ka1[4];
#pragma unroll
    for (int k4 = 0; k4 < 4; k4++)
      ka0[k4] = *(const short8*)(k + koff + (size_t)(cbase + l31) * 64 + k4 * 16 + hi * 8);
    if (haveMt1) {
#pragma unroll
      for (int k4 = 0; k4 < 4; k4++)
        ka1[k4] = *(const short8*)(k + koff + (size_t)(cbase + 32 + l31) * 64 + k4 * 16 + hi * 8);
    }
    // ---- issue V^T fragment loads early (A-op for PV: row=d, k=c) ----
    const int nct = haveMt1 ? 4 : 2;
    short8 va0[4], va1[4];
#pragma unroll
    for (int ct = 0; ct < 4; ct++) {
      if (ct < nct) {
        va0[ct] = *(const short8*)(vt + koff + (size_t)l31 * 2048 + cbase + ct * 16 + hi * 8);
        va1[ct] = *(const short8*)(vt + koff + (size_t)(32 + l31) * 2048 + cbase + ct * 16 + hi * 8);
      }
    }

    // ---- S^T = K · Q  (D col = q = l31, row = c-offset crow) ----
    f32x16 s0, s1;
#pragma unroll
    for (int r = 0; r < 16; r++) { s0[r] = 0.f; s1[r] = 0.f; }
#pragma unroll
    for (int k4 = 0; k4 < 4; k4++)
      s0 = __builtin_amdgcn_mfma_f32_32x32x16_bf16(ka0[k4], bq[k4], s0, 0, 0, 0);
    if (haveMt1) {
#pragma unroll
      for (int k4 = 0; k4 < 4; k4++)
        s1 = __builtin_amdgcn_mfma_f32_32x32x16_bf16(ka1[k4], bq[k4], s1, 0, 0, 0);
    }

    // scale to log2 domain; causal mask on the diagonal tile
#pragma unroll
    for (int r = 0; r < 16; r++) { s0[r] *= isc2; s1[r] *= isc2; }
    if (kt == KT) {
      const int thr = q0 + l31 - cbase;
#pragma unroll
      for (int r = 0; r < 16; r++) {
        const int crow = (r & 3) + 8 * (r >> 2) + 4 * hi;
        if (crow > thr) s0[r] = NINF;
        if (crow + 32 > thr) s1[r] = NINF;       // also kills unused s1 when !haveMt1
      }
    }

    // ---- online softmax: lane-local + one cross-half shuffle ----
    float mx = s0[0];
#pragma unroll
    for (int r = 1; r < 16; r++) mx = fmaxf(mx, s0[r]);
#pragma unroll
    for (int r = 0; r < 16; r++) mx = fmaxf(mx, s1[r]);
    mx = fmaxf(mx, __shfl_xor(mx, 32, 64));
    const float mn = fmaxf(m2, mx);
    const float rsc = exp2f(m2 - mn);
    m2 = mn;
    f32x16 p0, p1;
    float ps = 0.f;
#pragma unroll
    for (int r = 0; r < 16; r++) { p0[r] = exp2f(s0[r] - mn); ps += p0[r]; }
#pragma unroll
    for (int r = 0; r < 16; r++) { p1[r] = exp2f(s1[r] - mn); ps += p1[r]; }
    ps += __shfl_xor(ps, 32, 64);
    ell = ell * rsc + ps;
#pragma unroll
    for (int r = 0; r < 16; r++) { o0[r] *= rsc; o1[r] *= rsc; }

    // ---- pack P -> B-frags (cvt_pk + cross-half exchange) and PV ----
#pragma unroll
    for (int ct = 0; ct < 4; ct++) {
      if (ct < nct) {
        const f32x16& pp = (ct < 2) ? p0 : p1;
        const int rA = (ct & 1) * 8;
        unsigned pkA0 = pkbf(pp[rA + 0], pp[rA + 1]);
        unsigned pkA1 = pkbf(pp[rA + 2], pp[rA + 3]);
        unsigned pkB0 = pkbf(pp[rA + 4], pp[rA + 5]);
        unsigned pkB1 = pkbf(pp[rA + 6], pp[rA + 7]);
        unsigned u0 = (unsigned)__shfl_xor((int)(hi ? pkA0 : pkB0), 32, 64);
        unsigned u1 = (unsigned)__shfl_xor((int)(hi ? pkA1 : pkB1), 32, 64);
        u32x4v pu;
        pu[0] = hi ? u0 : pkA0;
        pu[1] = hi ? u1 : pkA1;
        pu[2] = hi ? pkB0 : u0;
        pu[3] = hi ? pkB1 : u1;
        short8 pf = __builtin_bit_cast(short8, pu);
        o0 = __builtin_amdgcn_mfma_f32_32x32x16_bf16(va0[ct], pf, o0, 0, 0, 0);
        o1 = __builtin_amdgcn_mfma_f32_32x32x16_bf16(va1[ct], pf, o1, 0, 0, 0);
      }
    }
  }

  // ---- epilogue: O^T -> ao[q][h*64+d]; 4 consecutive d per reg-quad ----
  const float invl = 1.0f / ell;
  u16* orow = ao + ((size_t)(b * 2048 + q0 + l31)) * 1024 + h * 64;
#pragma unroll
  for (int qd = 0; qd < 4; qd++) {
    us4 st0, st1;
#pragma unroll
    for (int j = 0; j < 4; j++) {
      st0[j] = f2bf(o0[qd * 4 + j] * invl);
      st1[j] = f2bf(o1[qd * 4 + j] * invl);
    }
    *(us4*)(orow + qd * 8 + hi * 4) = st0;          // d = 8qd+4hi+j
    *(us4*)(orow + 32 + qd * 8 + hi * 4) = st1;     // d = 32+8qd+4hi+j
  }
}

// --------------------------- output projection ------------------------------
__global__ __launch_bounds__(256) void gemm_out_kernel(const u16* __restrict__ ab,
                                                       const u16* __restrict__ wo,
                                                       float* __restrict__ out) {
  const int tm = blockIdx.x, tn = blockIdx.y;
  __shared__ __align__(16) u16 As[128 * 32];
  __shared__ __align__(16) u16 Bs[128 * 32];

  const int t = threadIdx.x, lane = t & 63, w = t >> 6;
  const int wm = w >> 1, wn = w & 1, lg = lane >> 4, lr = lane & 15;

  floatx4 acc[4][4];
#pragma unroll
  for (int i = 0; i < 4; i++)
#pragma unroll
    for (int j = 0; j < 4; j++) acc[i][j] = (floatx4){0.f, 0.f, 0.f, 0.f};

  const int rowA = tm * 128, rowB = tn * 128;
  for (int kt = 0; kt < 32; ++kt) {
#pragma unroll
    for (int s = 0; s < 2; s++) {
      int c = t + s * 256;
      int r = c >> 2, kc = c & 3;
      *(uint4v*)(As + r * 32 + kc * 8) =
          *(const uint4v*)(ab + (size_t)(rowA + r) * 1024 + kt * 32 + kc * 8);
      *(uint4v*)(Bs + r * 32 + kc * 8) =
          *(const uint4v*)(wo + (size_t)(rowB + r) * 1024 + kt * 32 + kc * 8);
    }
    __syncthreads();
    short8 af[4], bw[4];
#pragma unroll
    for (int i = 0; i < 4; i++)
      af[i] = *(const short8*)(As + (wm * 64 + i * 16 + lr) * 32 + lg * 8);
#pragma unroll
    for (int j = 0; j < 4; j++)
      bw[j] = *(const short8*)(Bs + (wn * 64 + j * 16 + lr) * 32 + lg * 8);
#pragma unroll
    for (int i = 0; i < 4; i++)
#pragma unroll
      for (int j = 0; j < 4; j++)
        acc[i][j] = __builtin_amdgcn_mfma_f32_16x16x32_bf16(af[i], bw[j], acc[i][j], 0, 0, 0);
    __syncthreads();
  }

  const int rowbase = tm * 128 + wm * 64, colbase = tn * 128 + wn * 64;
#pragma unroll
  for (int i = 0; i < 4; i++)
#pragma unroll
    for (int ii = 0; ii < 4; ii++) {
      int gm = rowbase + i * 16 + lg * 4 + ii;
#pragma unroll
      for (int j = 0; j < 4; j++) {
        int ge = colbase + j * 16 + lr;
        out[(size_t)gm * 1024 + ge] = acc[i][j][ii];
      }
    }
}

// ---------------------------------------------------------------------------
extern "C" void kernel_launch(void* const* d_in, const int* in_sizes, int n_in,
                              void* d_out, int out_size, void* d_ws, size_t ws_size,
                              hipStream_t stream) {
  const float* x     = (const float*)d_in[0];
  const float* Wq    = (const float*)d_in[1];
  const float* Wk    = (const float*)d_in[2];
  const float* Wv    = (const float*)d_in[3];
  const float* Wo    = (const float*)d_in[4];
  const float* alpha = (const float*)d_in[5];
  const float* Tb    = (const float*)d_in[6];
  const float* cw    = (const float*)d_in[7];
  const float* cb    = (const float*)d_in[8];
  const int*   tstep = (const int*)d_in[11];

  char* ws = (char*)d_ws;
  u16* xb  = (u16*)(ws + OFF_XB);
  u16* wqb = (u16*)(ws + OFF_WQ);
  u16* wkb = (u16*)(ws + OFF_WK);
  u16* wvb = (u16*)(ws + OFF_WV);
  u16* wob = (u16*)(ws + OFF_WO);
  u16* qb  = (u16*)(ws + OFF_Q);
  u16* kb  = (u16*)(ws + OFF_K);
  u16* vb  = (u16*)(ws + OFF_V);
  u16* aob = (u16*)(ws + OFF_AO);
  u16* vtb = (u16*)(ws + OFF_XB);           // aliases xb (dead after gemm_qkv)
  float* sc = (float*)(ws + OFF_SC);

  // bf16 converts
  cvt_kernel<<<4096, 256, 0, stream>>>(x, xb, 1048576);
  cvt_kernel<<<1024, 256, 0, stream>>>(Wq, wqb, 262144);
  cvt_kernel<<<1024, 256, 0, stream>>>(Wk, wkb, 262144);
  cvt_kernel<<<1024, 256, 0, stream>>>(Wv, wvb, 262144);
  cvt_kernel<<<1024, 256, 0, stream>>>(Wo, wob, 262144);

  // temperature scale
  hipMemsetAsync(sc + 2, 0, 2 * sizeof(float), stream);
  scale_partial_kernel<<<128, 256, 0, stream>>>(x, cw, sc + 2);
  scale_finalize_kernel<<<1, 64, 0, stream>>>(sc + 2, cb, alpha, Tb, tstep, sc);

  // QKV projection + RoPE
  gemm_qkv_kernel<<<dim3(32, 8, 3), 256, 0, stream>>>(xb, wqb, wkb, wvb, qb, kb, vb);

  // V -> V^T (into dead xb region)
  vtrans_kernel<<<dim3(32, 32), 256, 0, stream>>>(vb, vtb);

  // causal flash attention (LDS-free, balanced 32-row wave tiles)
  attn_kernel<<<dim3(512), 256, 0, stream>>>(qb, kb, vtb, aob, sc);

  // output projection
  gemm_out_kernel<<<dim3(32, 8), 256, 0, stream>>>(aob, wob, (float*)d_out);
}